// Round 12
// baseline (912.835 us; speedup 1.0000x reference)
//
#include <hip/hip_runtime.h>
#include <hip/hip_bf16.h>

// Problem constants
#define NB 512     // batch
#define NP 1152    // primary capsules
#define NC 10      // digit capsules
#define ND 16      // output capsule dim
#define NI 8       // input capsule dim

constexpr int K_B    = 2;                // b's per lane
constexpr int B_TILE = 4 * 4 * K_B;      // 32 b per block (4 waves x 4 bsub x K_B)
constexpr int P_TILE = 8;                // p's per W tile
constexpr int NPT    = 3;                // W tiles per block (24 p's/block)
constexpr int NBLK_B = NB / B_TILE;      // 16
constexpr int NBLK_P = NP / P_TILE;      // 144 W tiles
constexpr int NBLK_PO = NBLK_P / NPT;    // 48 partial slices
constexpr int SVD = NB * NC * ND;        // 81920
constexpr int W_TILE_BYTES = P_TILE * NC * ND * NI * 4;   // 40960
constexpr int X_TILE_FLOATS = B_TILE * P_TILE * NI;       // 2048 floats = 8KB

constexpr float LOG2E = 1.4426950408889634f;

typedef float v2f __attribute__((ext_vector_type(2)));

// 16-lane all-reduce sum via DPP (quad_perm xor1, xor2; row_ror 4, 8).
// Pure VALU. Result broadcast to all 16 lanes of the row.
__device__ __forceinline__ float red16_dpp(float v) {
    int t;
    t = __builtin_amdgcn_update_dpp(0, __float_as_int(v), 0xB1, 0xF, 0xF, true); // xor1
    v += __int_as_float(t);
    t = __builtin_amdgcn_update_dpp(0, __float_as_int(v), 0x4E, 0xF, 0xF, true); // xor2
    v += __int_as_float(t);
    t = __builtin_amdgcn_update_dpp(0, __float_as_int(v), 0x124, 0xF, 0xF, true); // row_ror:4
    v += __int_as_float(t);
    t = __builtin_amdgcn_update_dpp(0, __float_as_int(v), 0x128, 0xF, 0xF, true); // row_ror:8
    v += __int_as_float(t);
    return v;
}

// 4-lane all-reduce sum via DPP quad_perm (xor1, xor2). Broadcast to quad.
__device__ __forceinline__ float red4_dpp(float v) {
    int t;
    t = __builtin_amdgcn_update_dpp(0, __float_as_int(v), 0xB1, 0xF, 0xF, true); // xor1
    v += __int_as_float(t);
    t = __builtin_amdgcn_update_dpp(0, __float_as_int(v), 0x4E, 0xF, 0xF, true); // xor2
    v += __int_as_float(t);
    return v;
}

// One routing pass. R12 = R11 structure with the tt loop PINNED (#pragma unroll 1).
// R11 failure analysis: constant-bound tt loop was fully unrolled AND
// software-pipelined by LLVM -> all 3 tiles' global_load_lds address regs
// hoisted live simultaneously -> demand blew past the 128 cap -> scratch
// (VGPR=128 pinned, FETCH 147MB, WRITE 232MB, VALUBusy 10.7%). NEW LAW:
// multi-tile staging loops need #pragma unroll 1 on this compiler.
// R10 (clean, NPT=1) proved the two-stage concept: pass 73->63us, VALU 65%,
// but 3x46MB partial traffic ate the win. NPT=3 -> 48 slices (15.7MB):
// pass stores -30MB, reduce reads -30MB, grid 768 = exactly 3 blocks/CU.
// Grid swizzle (R9, kept): id%16 = bblk -> per-bblk XCD affinity, x L2-local.
// W LDS swizzle involution: S(A) = A ^ (bit7(A)<<4) ^ (bit8(A)<<5).
// x LDS swizzle (R4, verified): physical unit u holds logical (bl, w16^(bl&3))
//   -> read XOR (bsub<<4): bsub hits bank-quads {0,4,8,12}, conflict-free.
// Softmax slimming (R2, verified): log2(e) folded into vr, NO max-subtraction
// (|lg*log2e| <~ 50 << 127, exp2-safe), v_rcp_f32 for 1/sum.
// VGPR-cap law (confirmed 5x): bounds(_,N) -> cap 256/N; (256,2) -> 128;
// demand ~90 with unroll-1 -> no spill. Residency: LDS 48KB -> 3 blocks/CU.
// PASS 0: coup = 0.1;  PASS 1: logits = u.v0;  PASS 2: logits = u.(v0+v1)
template<int PASS, bool TS>
__global__ __launch_bounds__(256, 2)
void caps_pass(const float* __restrict__ x,    // [NB, NP, NI]
               const float* __restrict__ w,    // [NP, NC, ND, NI]
               const float* __restrict__ v0,   // [NB, NC, ND]
               const float* __restrict__ v1,   // [NB, NC, ND]
               float* __restrict__ s_out)      // TS: partial[NBLK_PO][SVD]; else s[SVD]
{
    __shared__ __align__(16) float w_lds[W_TILE_BYTES / 4];   // 40KB
    __shared__ __align__(16) float x_lds[X_TILE_FLOATS];      // 8KB, [b][pp][i] swizzled

    const int tid  = threadIdx.x;
    const int lane = tid & 63;
    const int wave = tid >> 6;           // 0..3
    const int d    = lane & 15;
    const int bsub = lane >> 4;          // 0..3
    // R9 swizzle: id = pblk_out*16 + bblk -> id%8 = bblk%8 -> XCD affinity.
    const int bblk     = blockIdx.x % NBLK_B;
    const int pblk_out = blockIdx.x / NBLK_B;   // 0..47

    // W source swizzle offset: S(lane*16) within each 1KB chunk
    const int lane_src = (lane << 4) ^ ((lane & 8) << 1) ^ ((lane & 16) << 1);

    int bidx[K_B];
    #pragma unroll
    for (int k = 0; k < K_B; ++k) bidx[k] = bblk * B_TILE + wave * 8 + k * 4 + bsub;

    // v (v0, or v0+v1 for pass 2), pre-scaled by log2(e) — loop-invariant
    float vr[K_B][NC];
    if (PASS >= 1) {
        #pragma unroll
        for (int k = 0; k < K_B; ++k)
            #pragma unroll
            for (int c = 0; c < NC; ++c) {
                float vv = v0[(bidx[k] * NC + c) * ND + d];
                if (PASS == 2) vv += v1[(bidx[k] * NC + c) * ND + d];
                vr[k][c] = vv * LOG2E;
            }
    }

    float sacc[K_B][NC];
    #pragma unroll
    for (int k = 0; k < K_B; ++k)
        #pragma unroll
        for (int c = 0; c < NC; ++c) sacc[k][c] = 0.0f;

    // swizzled read offset for W[pp,c,d,0:4]: A = d*32 -> A ^ (bit2(d)<<4) ^ (bit3(d)<<5)
    const int lane_rd = (d << 5) ^ ((d & 4) << 2) ^ ((d & 8) << 2);
    const int xswz    = bsub << 4;   // x read swizzle (byte bits 4-5 ^= b&3)

    // R12: unroll 1 is LOAD-BEARING — prevents the staging pipeliner from
    // hoisting 3 tiles' load-address registers (the R11 spill).
    #pragma unroll 1
    for (int tt = 0; tt < NPT; ++tt) {
        const int pblk = pblk_out * NPT + tt;
        const int p0   = pblk * P_TILE;

        // ---- stage W tile (16B/lane, linear dest, swizzled source) ----
        {
            const uint8_t* wsrc = (const uint8_t*)w + (size_t)pblk * W_TILE_BYTES;
            #pragma unroll
            for (int j = 0; j < 10; ++j) {
                const int off = wave * 10240 + j * 1024;
                __builtin_amdgcn_global_load_lds(
                    (const __attribute__((address_space(1))) void*)(wsrc + off + lane_src),
                    (__attribute__((address_space(3))) void*)((uint8_t*)w_lds + off),
                    16, 0, 0);
            }
        }

        // ---- stage x tile: 8KB, linear dest, swizzled source strips ----
        {
            #pragma unroll
            for (int j = 0; j < 2; ++j) {
                const int u   = wave * 128 + j * 64 + lane;
                const int bl  = u >> 4;
                const int w16 = u & 15;
                const float* bbase = x + ((size_t)(bblk * B_TILE + bl) * NP + p0) * NI;
                const uint8_t* src = (const uint8_t*)bbase + ((w16 ^ (bl & 3)) * 16);
                __builtin_amdgcn_global_load_lds(
                    (const __attribute__((address_space(1))) void*)src,
                    (__attribute__((address_space(3))) void*)((uint8_t*)x_lds + (size_t)u * 16),
                    16, 0, 0);
            }
        }

        asm volatile("s_waitcnt vmcnt(0)" ::: "memory");   // staging complete
        __syncthreads();                                   // visible to all waves

        for (int pp = 0; pp < P_TILE; ++pp) {
            v2f xv[K_B][4];
            #pragma unroll
            for (int k = 0; k < K_B; ++k) {
                const int xb = ((wave * 8 + k * 4 + bsub) * 256 + pp * 32) ^ xswz;
                const uint8_t* xp = (const uint8_t*)x_lds;
                const float4 a = *(const float4*)(xp + xb);
                const float4 b = *(const float4*)(xp + (xb ^ 16));
                xv[k][0] = v2f{a.x, a.y};
                xv[k][1] = v2f{a.z, a.w};
                xv[k][2] = v2f{b.x, b.y};
                xv[k][3] = v2f{b.z, b.w};
            }

            float uh[K_B][NC];
            #pragma unroll
            for (int c = 0; c < NC; ++c) {
                const uint8_t* pb = (const uint8_t*)w_lds + pp * 5120 + c * 512;
                const float4 wa = *(const float4*)(pb + lane_rd);          // W[p,c,d,0:4]
                const float4 wb = *(const float4*)(pb + (lane_rd ^ 16));   // W[p,c,d,4:8]
                const v2f w01{wa.x, wa.y}, w23{wa.z, wa.w};
                const v2f w45{wb.x, wb.y}, w67{wb.z, wb.w};
                #pragma unroll
                for (int k = 0; k < K_B; ++k) {
                    v2f acc = w01 * xv[k][0];                              // v_pk_mul_f32
                    acc = __builtin_elementwise_fma(w23, xv[k][1], acc);   // v_pk_fma_f32
                    acc = __builtin_elementwise_fma(w45, xv[k][2], acc);
                    acc = __builtin_elementwise_fma(w67, xv[k][3], acc);
                    const float u = acc[0] + acc[1];
                    if (PASS == 0) sacc[k][c] = fmaf(0.1f, u, sacc[k][c]);
                    else           uh[k][c] = u;
                }
            }

            if (PASS >= 1) {
                #pragma unroll
                for (int k = 0; k < K_B; ++k) {
                    float lg[NC];
                    #pragma unroll
                    for (int c = 0; c < NC; ++c)
                        lg[c] = red16_dpp(uh[k][c] * vr[k][c]);   // log2-domain logits
                    float ssum = 0.0f;
                    float coup[NC];
                    #pragma unroll
                    for (int c = 0; c < NC; ++c) {
                        coup[c] = __builtin_amdgcn_exp2f(lg[c]);  // no max-sub: bounded
                        ssum += coup[c];
                    }
                    const float inv = __builtin_amdgcn_rcpf(ssum);
                    #pragma unroll
                    for (int c = 0; c < NC; ++c)
                        sacc[k][c] = fmaf(coup[c] * inv, uh[k][c], sacc[k][c]);
                }
            }
        }

        if (tt + 1 < NPT) __syncthreads();   // LDS safe to overwrite next tt
    }

    // tail: each thread owns distinct (b,d). TS: plain stores into this
    // pblk_out's private slice (fire-and-forget). Legacy: device atomics.
    if (TS) {
        float* pout = s_out + (size_t)pblk_out * SVD;
        #pragma unroll
        for (int k = 0; k < K_B; ++k)
            #pragma unroll
            for (int c = 0; c < NC; ++c)
                pout[(bidx[k] * NC + c) * ND + d] = sacc[k][c];
    } else {
        #pragma unroll
        for (int k = 0; k < K_B; ++k)
            #pragma unroll
            for (int c = 0; c < NC; ++c)
                atomicAdd(&s_out[(bidx[k] * NC + c) * ND + d], sacc[k][c]);
    }
}

// Fused reduce (sum over 48 pblk slices) + squash, float4-vectorized.
// Thread g handles 4 consecutive floats (base = g*4); a d-row (16 floats) =
// 4 consecutive threads = one lane-quad -> 4-lane DPP reduce for |s|^2.
// 15.7MB reads, coalesced 1KB/wave/instr, mostly L2/L3-resident.
__global__ __launch_bounds__(256)
void caps_reduce_squash(const float* __restrict__ part, float* __restrict__ v)
{
    const int g = blockIdx.x * 256 + threadIdx.x;     // 0 .. SVD/4-1
    const float4* p4 = (const float4*)part;
    float4 a0{0,0,0,0}, a1{0,0,0,0}, a2{0,0,0,0}, a3{0,0,0,0};
    #pragma unroll
    for (int r = 0; r < NBLK_PO; r += 4) {
        const float4 t0 = p4[(size_t)(r + 0) * (SVD / 4) + g];
        const float4 t1 = p4[(size_t)(r + 1) * (SVD / 4) + g];
        const float4 t2 = p4[(size_t)(r + 2) * (SVD / 4) + g];
        const float4 t3 = p4[(size_t)(r + 3) * (SVD / 4) + g];
        a0.x += t0.x; a0.y += t0.y; a0.z += t0.z; a0.w += t0.w;
        a1.x += t1.x; a1.y += t1.y; a1.z += t1.z; a1.w += t1.w;
        a2.x += t2.x; a2.y += t2.y; a2.z += t2.z; a2.w += t2.w;
        a3.x += t3.x; a3.y += t3.y; a3.z += t3.z; a3.w += t3.w;
    }
    float4 sv;
    sv.x = (a0.x + a1.x) + (a2.x + a3.x);
    sv.y = (a0.y + a1.y) + (a2.y + a3.y);
    sv.z = (a0.z + a1.z) + (a2.z + a3.z);
    sv.w = (a0.w + a1.w) + (a2.w + a3.w);
    const float sql = ((sv.x * sv.x + sv.y * sv.y) + (sv.z * sv.z + sv.w * sv.w));
    const float sq  = red4_dpp(sql);                  // sum over the d-row's quad
    const float scale = (sq / (1.0f + sq)) / sqrtf(sq + 1e-7f);
    sv.x *= scale; sv.y *= scale; sv.z *= scale; sv.w *= scale;
    ((float4*)v)[g] = sv;
}

// Legacy squash (fallback path). ZERO_S re-zeros s for the next pass.
template<bool ZERO_S>
__global__ __launch_bounds__(256)
void caps_squash(float* __restrict__ s, float* __restrict__ v)
{
    const int idx = blockIdx.x * 256 + threadIdx.x;
    const float sv = s[idx];
    if (ZERO_S) s[idx] = 0.0f;
    float sq = red16_dpp(sv * sv);
    const float scale = (sq / (1.0f + sq)) / sqrtf(sq + 1e-7f);
    v[idx] = scale * sv;
}

extern "C" void kernel_launch(void* const* d_in, const int* in_sizes, int n_in,
                              void* d_out, int out_size, void* d_ws, size_t ws_size,
                              hipStream_t stream)
{
    const float* x = (const float*)d_in[0];
    const float* w = (const float*)d_in[1];
    float* out = (float*)d_out;

    const dim3 pgrid(NBLK_B * NBLK_PO);  // 768 blocks of 256 (3/CU exactly)
    const dim3 pblock(256);
    const dim3 rgrid(SVD / 4 / 256);     // 80
    const dim3 rblock(256);

    const size_t partBytes = (size_t)NBLK_PO * SVD * sizeof(float);  // ~15.7MB

    if (ws_size >= partBytes + (size_t)SVD * sizeof(float)) {
        // ---- two-stage path: no atomics, no memset ----
        float* part = (float*)d_ws;                                  // [NBLK_PO][SVD]
        float* v0   = (float*)((uint8_t*)d_ws + partBytes);          // [SVD]

        caps_pass<0, true><<<pgrid, pblock, 0, stream>>>(x, w, nullptr, nullptr, part);
        caps_reduce_squash<<<rgrid, rblock, 0, stream>>>(part, v0);
        caps_pass<1, true><<<pgrid, pblock, 0, stream>>>(x, w, v0, nullptr, part);
        caps_reduce_squash<<<rgrid, rblock, 0, stream>>>(part, out);   // v1 = out
        caps_pass<2, true><<<pgrid, pblock, 0, stream>>>(x, w, v0, out, part);
        caps_reduce_squash<<<rgrid, rblock, 0, stream>>>(part, out);
    } else {
        // ---- fallback: atomic path ----
        float* s  = (float*)d_ws;       // [SVD]
        float* v0 = s + SVD;            // [SVD]
        const dim3 qgrid(SVD / 256);    // 320
        const dim3 qblock(256);

        hipMemsetAsync(s, 0, (size_t)SVD * sizeof(float), stream);
        caps_pass<0, false><<<pgrid, pblock, 0, stream>>>(x, w, nullptr, nullptr, s);
        caps_squash<true><<<qgrid, qblock, 0, stream>>>(s, v0);
        caps_pass<1, false><<<pgrid, pblock, 0, stream>>>(x, w, v0, nullptr, s);
        caps_squash<true><<<qgrid, qblock, 0, stream>>>(s, out);
        caps_pass<2, false><<<pgrid, pblock, 0, stream>>>(x, w, v0, out, s);
        caps_squash<false><<<qgrid, qblock, 0, stream>>>(s, out);
    }
}

// Round 13
// 210.272 us; speedup vs baseline: 4.3412x; 4.3412x over previous
//
#include <hip/hip_runtime.h>
#include <hip/hip_bf16.h>

// Problem constants
#define NB 512     // batch
#define NP 1152    // primary capsules
#define NC 10      // digit capsules
#define ND 16      // output capsule dim
#define NI 8       // input capsule dim

constexpr int K_B    = 2;                // b's per lane
constexpr int B_TILE = 4 * 4 * K_B;      // 32 b per block (4 waves x 4 bsub x K_B)
constexpr int P_TILE = 8;                // p's per W tile
constexpr int NBLK_B = NB / B_TILE;      // 16
constexpr int NBLK_P = NP / P_TILE;      // 144 partial slices
constexpr int SVD = NB * NC * ND;        // 81920
constexpr int W_TILE_BYTES = P_TILE * NC * ND * NI * 4;   // 40960
constexpr int X_TILE_FLOATS = B_TILE * P_TILE * NI;       // 2048 floats = 8KB

constexpr float LOG2E = 1.4426950408889634f;

typedef float v2f __attribute__((ext_vector_type(2)));

// 16-lane all-reduce sum via DPP (quad_perm xor1, xor2; row_ror 4, 8).
// Pure VALU. Result broadcast to all 16 lanes of the row.
__device__ __forceinline__ float red16_dpp(float v) {
    int t;
    t = __builtin_amdgcn_update_dpp(0, __float_as_int(v), 0xB1, 0xF, 0xF, true); // xor1
    v += __int_as_float(t);
    t = __builtin_amdgcn_update_dpp(0, __float_as_int(v), 0x4E, 0xF, 0xF, true); // xor2
    v += __int_as_float(t);
    t = __builtin_amdgcn_update_dpp(0, __float_as_int(v), 0x124, 0xF, 0xF, true); // row_ror:4
    v += __int_as_float(t);
    t = __builtin_amdgcn_update_dpp(0, __float_as_int(v), 0x128, 0xF, 0xF, true); // row_ror:8
    v += __int_as_float(t);
    return v;
}

// One routing pass. R13 = EXACT R10 pass (the cleanest measured: VGPR 80,
// 62-65us profiled, VALU 65%) — single W tile per block, no multi-tile loop.
// NPT multi-tile accumulation is ABANDONED: R11 (unrolled+pipelined) and R12
// (#pragma unroll 1) both blew past the 128-VGPR cap into deep scratch
// (WRITE 232MB..1.48GB). The two-stage structure is kept; the reduce kernel
// is where R13 improves (R10's reduce ~10us each cancelled its pass gains).
// Grid swizzle (R9): id%16 = bblk -> per-bblk XCD affinity, x L2-local.
// W LDS swizzle involution: S(A) = A ^ (bit7(A)<<4) ^ (bit8(A)<<5).
// x LDS swizzle (R4, verified): physical unit u holds logical (bl, w16^(bl&3))
//   -> read XOR (bsub<<4): bsub hits bank-quads {0,4,8,12}, conflict-free.
// Softmax slimming (R2, verified): log2(e) folded into vr, NO max-subtraction
// (|lg*log2e| <~ 50 << 127, exp2-safe), v_rcp_f32 for 1/sum.
// VGPR-cap law (confirmed 5x): bounds(_,N) -> cap 256/N; (256,2) -> 128 >>
// demand ~80 -> no spill. Residency: LDS 48KB -> 3 blocks/CU, 12 waves/CU.
// PASS 0: coup = 0.1;  PASS 1: logits = u.v0;  PASS 2: logits = u.(v0+v1)
template<int PASS, bool TS>
__global__ __launch_bounds__(256, 2)
void caps_pass(const float* __restrict__ x,    // [NB, NP, NI]
               const float* __restrict__ w,    // [NP, NC, ND, NI]
               const float* __restrict__ v0,   // [NB, NC, ND]
               const float* __restrict__ v1,   // [NB, NC, ND]
               float* __restrict__ s_out)      // TS: partial[NBLK_P][SVD]; else s[SVD]
{
    __shared__ __align__(16) float w_lds[W_TILE_BYTES / 4];   // 40KB
    __shared__ __align__(16) float x_lds[X_TILE_FLOATS];      // 8KB, [b][pp][i] swizzled

    const int tid  = threadIdx.x;
    const int lane = tid & 63;
    const int wave = tid >> 6;           // 0..3
    const int d    = lane & 15;
    const int bsub = lane >> 4;          // 0..3
    // R9 swizzle: id = pblk*16 + bblk -> id%8 = bblk%8 -> XCD affinity.
    const int bblk = blockIdx.x % NBLK_B;
    const int pblk = blockIdx.x / NBLK_B;
    const int p0   = pblk * P_TILE;

    // ---- stage W tile: each wave loads one 10KB quarter (16B/lane, linear dest) ----
    {
        const uint8_t* wsrc = (const uint8_t*)w + (size_t)pblk * W_TILE_BYTES;
        // source offset: S(lane*16) within the 1KB chunk (bits 7,8 of chunk bases are 0)
        const int lane_src = (lane << 4) ^ ((lane & 8) << 1) ^ ((lane & 16) << 1);
        #pragma unroll
        for (int j = 0; j < 10; ++j) {
            const int off = wave * 10240 + j * 1024;
            __builtin_amdgcn_global_load_lds(
                (const __attribute__((address_space(1))) void*)(wsrc + off + lane_src),
                (__attribute__((address_space(3))) void*)((uint8_t*)w_lds + off),
                16, 0, 0);
        }
    }

    // ---- stage x tile: 8KB, linear LDS dest, swizzled global source ----
    // 16B unit u (0..511): bl = u>>4 (0..31), w16 = u&15 (= pp*2+half).
    // Physical LDS unit u holds logical unit (bl, w16 ^ (bl&3)) [byte bits 4-5].
    // Source strips stay 256B-contiguous per b.
    {
        #pragma unroll
        for (int j = 0; j < 2; ++j) {
            const int u   = wave * 128 + j * 64 + lane;
            const int bl  = u >> 4;
            const int w16 = u & 15;
            const float* bbase = x + ((size_t)(bblk * B_TILE + bl) * NP + p0) * NI;
            const uint8_t* src = (const uint8_t*)bbase + ((w16 ^ (bl & 3)) * 16);
            __builtin_amdgcn_global_load_lds(
                (const __attribute__((address_space(1))) void*)src,
                (__attribute__((address_space(3))) void*)((uint8_t*)x_lds + (size_t)u * 16),
                16, 0, 0);
        }
    }

    int bidx[K_B];
    #pragma unroll
    for (int k = 0; k < K_B; ++k) bidx[k] = bblk * B_TILE + wave * 8 + k * 4 + bsub;

    // v (v0, or v0+v1 for pass 2), pre-scaled by log2(e) — loop-invariant over p
    float vr[K_B][NC];
    if (PASS >= 1) {
        #pragma unroll
        for (int k = 0; k < K_B; ++k)
            #pragma unroll
            for (int c = 0; c < NC; ++c) {
                float vv = v0[(bidx[k] * NC + c) * ND + d];
                if (PASS == 2) vv += v1[(bidx[k] * NC + c) * ND + d];
                vr[k][c] = vv * LOG2E;
            }
    }

    float sacc[K_B][NC];
    #pragma unroll
    for (int k = 0; k < K_B; ++k)
        #pragma unroll
        for (int c = 0; c < NC; ++c) sacc[k][c] = 0.0f;

    // swizzled read offset for W[pp,c,d,0:4]: A = d*32 -> A ^ (bit2(d)<<4) ^ (bit3(d)<<5).
    // Half 2 at A+16 = lane_rd^16 (bit4 flip, bits 7,8 unchanged).
    const int lane_rd = (d << 5) ^ ((d & 4) << 2) ^ ((d & 8) << 2);
    const int xswz    = bsub << 4;   // x read swizzle (byte bits 4-5 ^= b&3)

    asm volatile("s_waitcnt vmcnt(0)" ::: "memory");   // W + x staging complete
    __syncthreads();                                   // all quarters visible to all waves

    for (int pp = 0; pp < P_TILE; ++pp) {
        v2f xv[K_B][4];
        #pragma unroll
        for (int k = 0; k < K_B; ++k) {
            const int xb = ((wave * 8 + k * 4 + bsub) * 256 + pp * 32) ^ xswz;
            const uint8_t* xp = (const uint8_t*)x_lds;
            const float4 a = *(const float4*)(xp + xb);
            const float4 b = *(const float4*)(xp + (xb ^ 16));
            xv[k][0] = v2f{a.x, a.y};
            xv[k][1] = v2f{a.z, a.w};
            xv[k][2] = v2f{b.x, b.y};
            xv[k][3] = v2f{b.z, b.w};
        }

        float uh[K_B][NC];
        #pragma unroll
        for (int c = 0; c < NC; ++c) {
            const uint8_t* pb = (const uint8_t*)w_lds + pp * 5120 + c * 512;
            const float4 wa = *(const float4*)(pb + lane_rd);          // W[p,c,d,0:4]
            const float4 wb = *(const float4*)(pb + (lane_rd ^ 16));   // W[p,c,d,4:8]
            const v2f w01{wa.x, wa.y}, w23{wa.z, wa.w};
            const v2f w45{wb.x, wb.y}, w67{wb.z, wb.w};
            #pragma unroll
            for (int k = 0; k < K_B; ++k) {
                v2f acc = w01 * xv[k][0];                              // v_pk_mul_f32
                acc = __builtin_elementwise_fma(w23, xv[k][1], acc);   // v_pk_fma_f32
                acc = __builtin_elementwise_fma(w45, xv[k][2], acc);
                acc = __builtin_elementwise_fma(w67, xv[k][3], acc);
                const float u = acc[0] + acc[1];
                if (PASS == 0) sacc[k][c] = fmaf(0.1f, u, sacc[k][c]);
                else           uh[k][c] = u;
            }
        }

        if (PASS >= 1) {
            #pragma unroll
            for (int k = 0; k < K_B; ++k) {
                float lg[NC];
                #pragma unroll
                for (int c = 0; c < NC; ++c)
                    lg[c] = red16_dpp(uh[k][c] * vr[k][c]);   // log2-domain logits
                float ssum = 0.0f;
                float coup[NC];
                #pragma unroll
                for (int c = 0; c < NC; ++c) {
                    coup[c] = __builtin_amdgcn_exp2f(lg[c]);  // no max-sub: bounded
                    ssum += coup[c];
                }
                const float inv = __builtin_amdgcn_rcpf(ssum);
                #pragma unroll
                for (int c = 0; c < NC; ++c)
                    sacc[k][c] = fmaf(coup[c] * inv, uh[k][c], sacc[k][c]);
            }
        }
    }

    // tail: each thread owns distinct (b,d). TS: plain stores into this
    // pblk's private slice (fire-and-forget). Legacy: device atomics.
    if (TS) {
        float* pout = s_out + (size_t)pblk * SVD;
        #pragma unroll
        for (int k = 0; k < K_B; ++k)
            #pragma unroll
            for (int c = 0; c < NC; ++c)
                pout[(bidx[k] * NC + c) * ND + d] = sacc[k][c];
    } else {
        #pragma unroll
        for (int k = 0; k < K_B; ++k)
            #pragma unroll
            for (int c = 0; c < NC; ++c)
                atomicAdd(&s_out[(bidx[k] * NC + c) * ND + d], sacc[k][c]);
    }
}

// R13: split-slice fused reduce + squash.
// R10's reduce (one thread = one float, 144-deep chain, 5 waves/CU) cost
// ~10us each and cancelled the pass gains. R13: 256-thread blocks where
// threads 0-127 sum slices 0-71 of float g, threads 128-255 sum slices
// 72-143; combine via one LDS exchange; squash (16-lane d-row reduce) on the
// lower half. Grid 640 (2560 waves, ~10/CU) — 2x parallelism, half the
// serial chain, 4-way accumulator ILP.
__global__ __launch_bounds__(256)
void caps_reduce_squash(const float* __restrict__ part, float* __restrict__ v)
{
    __shared__ float sh[128];
    const int tid  = threadIdx.x;
    const int gl   = tid & 127;               // local float index
    const int half = tid >> 7;                // 0 or 1
    const int g    = blockIdx.x * 128 + gl;   // global float index
    const int r0   = half * (NBLK_P / 2);     // 0 or 72

    float a0 = 0, a1 = 0, a2 = 0, a3 = 0;
    #pragma unroll
    for (int r = 0; r < NBLK_P / 2; r += 4) {
        a0 += part[(size_t)(r0 + r + 0) * SVD + g];
        a1 += part[(size_t)(r0 + r + 1) * SVD + g];
        a2 += part[(size_t)(r0 + r + 2) * SVD + g];
        a3 += part[(size_t)(r0 + r + 3) * SVD + g];
    }
    float s = (a0 + a1) + (a2 + a3);
    if (half) sh[gl] = s;
    __syncthreads();
    if (!half) {
        s += sh[gl];
        // d-row = 16 consecutive g's; lane&15 == g&15 (128 % 16 == 0).
        float sq = red16_dpp(s * s);
        const float scale = (sq / (1.0f + sq)) / sqrtf(sq + 1e-7f);
        v[g] = scale * s;
    }
}

// Legacy squash (fallback path). ZERO_S re-zeros s for the next pass.
template<bool ZERO_S>
__global__ __launch_bounds__(256)
void caps_squash(float* __restrict__ s, float* __restrict__ v)
{
    const int idx = blockIdx.x * 256 + threadIdx.x;
    const float sv = s[idx];
    if (ZERO_S) s[idx] = 0.0f;
    float sq = red16_dpp(sv * sv);
    const float scale = (sq / (1.0f + sq)) / sqrtf(sq + 1e-7f);
    v[idx] = scale * sv;
}

extern "C" void kernel_launch(void* const* d_in, const int* in_sizes, int n_in,
                              void* d_out, int out_size, void* d_ws, size_t ws_size,
                              hipStream_t stream)
{
    const float* x = (const float*)d_in[0];
    const float* w = (const float*)d_in[1];
    float* out = (float*)d_out;

    const dim3 pgrid(NBLK_B * NBLK_P);   // 2304 blocks of 256 (3/CU)
    const dim3 pblock(256);
    const dim3 rgrid(SVD / 128);         // 640
    const dim3 rblock(256);

    const size_t partBytes = (size_t)NBLK_P * SVD * sizeof(float);   // ~47.2MB

    if (ws_size >= partBytes + (size_t)SVD * sizeof(float)) {
        // ---- two-stage path: no atomics, no memset ----
        float* part = (float*)d_ws;                                  // [NBLK_P][SVD]
        float* v0   = (float*)((uint8_t*)d_ws + partBytes);          // [SVD]

        caps_pass<0, true><<<pgrid, pblock, 0, stream>>>(x, w, nullptr, nullptr, part);
        caps_reduce_squash<<<rgrid, rblock, 0, stream>>>(part, v0);
        caps_pass<1, true><<<pgrid, pblock, 0, stream>>>(x, w, v0, nullptr, part);
        caps_reduce_squash<<<rgrid, rblock, 0, stream>>>(part, out);   // v1 = out
        caps_pass<2, true><<<pgrid, pblock, 0, stream>>>(x, w, v0, out, part);
        caps_reduce_squash<<<rgrid, rblock, 0, stream>>>(part, out);
    } else {
        // ---- fallback: atomic path ----
        float* s  = (float*)d_ws;       // [SVD]
        float* v0 = s + SVD;            // [SVD]
        const dim3 qgrid(SVD / 256);    // 320
        const dim3 qblock(256);

        hipMemsetAsync(s, 0, (size_t)SVD * sizeof(float), stream);
        caps_pass<0, false><<<pgrid, pblock, 0, stream>>>(x, w, nullptr, nullptr, s);
        caps_squash<true><<<qgrid, qblock, 0, stream>>>(s, v0);
        caps_pass<1, false><<<pgrid, pblock, 0, stream>>>(x, w, v0, nullptr, s);
        caps_squash<true><<<qgrid, qblock, 0, stream>>>(s, out);
        caps_pass<2, false><<<pgrid, pblock, 0, stream>>>(x, w, v0, out, s);
        caps_squash<false><<<qgrid, qblock, 0, stream>>>(s, out);
    }
}

// Round 14
// 192.589 us; speedup vs baseline: 4.7398x; 1.0918x over previous
//
#include <hip/hip_runtime.h>
#include <hip/hip_bf16.h>

// Problem constants
#define NB 512     // batch
#define NP 1152    // primary capsules
#define NC 10      // digit capsules
#define ND 16      // output capsule dim
#define NI 8       // input capsule dim

constexpr int K_B    = 2;                // b's per lane
constexpr int B_TILE = 4 * 4 * K_B;      // 32 b per block (4 waves x 4 bsub x K_B)
constexpr int P_TILE = 8;                // p's per block (two 4-p halves through one buffer)
constexpr int NBLK_B = NB / B_TILE;      // 16
constexpr int NBLK_P = NP / P_TILE;      // 144
constexpr int SVD = NB * NC * ND;        // 81920
constexpr int W_TILE_BYTES = P_TILE * NC * ND * NI * 4;   // 40960
constexpr int W_HALF_BYTES = W_TILE_BYTES / 2;            // 20480 (4 p's)
constexpr int X_TILE_FLOATS = B_TILE * P_TILE * NI;       // 2048 floats = 8KB

constexpr float LOG2E = 1.4426950408889634f;

typedef float v2f __attribute__((ext_vector_type(2)));

// 16-lane all-reduce sum via DPP (quad_perm xor1, xor2; row_ror 4, 8).
// Pure VALU. Result broadcast to all 16 lanes of the row.
__device__ __forceinline__ float red16_dpp(float v) {
    int t;
    t = __builtin_amdgcn_update_dpp(0, __float_as_int(v), 0xB1, 0xF, 0xF, true); // xor1
    v += __int_as_float(t);
    t = __builtin_amdgcn_update_dpp(0, __float_as_int(v), 0x4E, 0xF, 0xF, true); // xor2
    v += __int_as_float(t);
    t = __builtin_amdgcn_update_dpp(0, __float_as_int(v), 0x124, 0xF, 0xF, true); // row_ror:4
    v += __int_as_float(t);
    t = __builtin_amdgcn_update_dpp(0, __float_as_int(v), 0x128, 0xF, 0xF, true); // row_ror:8
    v += __int_as_float(t);
    return v;
}

// One routing pass. R14 = R9 (best total, 180.7us) + two-half W staging at
// (256,2) for occupancy. Evidence: clean no-atomic pass = 63-65us profiled
// at only 8.2 waves/CU (LDS 48KB caps 3 blocks/CU); LDS-pipe model ~35us +
// VALU ~21us -> ~25us is unhidden latency; occupancy ladder (8w->97, 12w->73)
// says waves/CU is the remaining lever. 28KB LDS (20KB W-half + 8KB x) ->
// LDS allows 5 blocks/CU; VGPR tier (<=128) allows 16 waves/CU -> 4 blocks
// x 4 waves resident (~1.4x). R6 tried this structure and spilled ONLY
// because (256,3) caps VGPR at 84; demand is ~104; (256,2) caps at 128.
// Straight-line staging (no lambdas), pp loops contain no staging (safe to
// unroll; the R11/R12 scratch disasters were loops holding sacc ACROSS
// global_load_lds staging).
// Two-stage/partial tail ABANDONED: partial-traffic tax (~30us) cancels the
// ~10us/pass atomic saving (R10 182.4, R13 210.3 vs R9 180.7). Tail = atomic.
// Grid swizzle (R9): id%16 = bblk -> per-bblk XCD affinity, x L2-local.
// W LDS swizzle involution: S(A) = A ^ (bit7(A)<<4) ^ (bit8(A)<<5); all
//   staged chunk bases (wave*5120 + j*1024 + h*20480) have bits 7,8 == 0.
// x LDS swizzle (R4): physical unit u holds logical (bl, w16^(bl&3));
//   read XOR (bsub<<4) -> bsub hits bank-quads {0,4,8,12}, conflict-free.
// Softmax slimming (R2): log2(e) folded into vr, NO max-subtraction
//   (|lg*log2e| <~ 50 << 127, exp2-safe), v_rcp_f32 for 1/sum.
// VGPR-cap law (confirmed 5x): bounds(_,N) -> cap 256/N, independent of
//   block size. Cap below demand = silent scratch spill (FETCH/WRITE blow-up).
// PASS 0: coup = 0.1;  PASS 1: logits = u.v0;  PASS 2: logits = u.(v0+v1)
template<int PASS>
__global__ __launch_bounds__(256, 2)
void caps_pass(const float* __restrict__ x,    // [NB, NP, NI]
               const float* __restrict__ w,    // [NP, NC, ND, NI]
               const float* __restrict__ v0,   // [NB, NC, ND]
               const float* __restrict__ v1,   // [NB, NC, ND]
               float* __restrict__ s_out)      // [NB, NC, ND]
{
    __shared__ __align__(16) float w_lds[W_HALF_BYTES / 4];   // 20KB (4 p's)
    __shared__ __align__(16) float x_lds[X_TILE_FLOATS];      // 8KB, [b][pp][i] swizzled

    const int tid  = threadIdx.x;
    const int lane = tid & 63;
    const int wave = tid >> 6;           // 0..3
    const int d    = lane & 15;
    const int bsub = lane >> 4;          // 0..3
    // R9 swizzle: id = pblk*16 + bblk -> id%8 = bblk%8 -> XCD affinity.
    const int bblk = blockIdx.x % NBLK_B;
    const int pblk = blockIdx.x / NBLK_B;
    const int p0   = pblk * P_TILE;

    // W source swizzle offset: S(lane*16) within each 1KB chunk.
    const int lane_src = (lane << 4) ^ ((lane & 8) << 1) ^ ((lane & 16) << 1);
    const uint8_t* wsrc = (const uint8_t*)w + (size_t)pblk * W_TILE_BYTES;

    // ---- stage W half 0 (4 p's, 20KB): each wave 5KB, linear dest ----
    #pragma unroll
    for (int j = 0; j < 5; ++j) {
        const int off = wave * 5120 + j * 1024;
        __builtin_amdgcn_global_load_lds(
            (const __attribute__((address_space(1))) void*)(wsrc + off + lane_src),
            (__attribute__((address_space(3))) void*)((uint8_t*)w_lds + off),
            16, 0, 0);
    }

    // ---- stage x tile: 8KB, linear LDS dest, swizzled global source ----
    // 16B unit u (0..511): bl = u>>4 (0..31), w16 = u&15 (= pp*2+half).
    // Physical LDS unit u holds logical unit (bl, w16 ^ (bl&3)) [byte bits 4-5].
    #pragma unroll
    for (int j = 0; j < 2; ++j) {
        const int u   = wave * 128 + j * 64 + lane;
        const int bl  = u >> 4;
        const int w16 = u & 15;
        const float* bbase = x + ((size_t)(bblk * B_TILE + bl) * NP + p0) * NI;
        const uint8_t* src = (const uint8_t*)bbase + ((w16 ^ (bl & 3)) * 16);
        __builtin_amdgcn_global_load_lds(
            (const __attribute__((address_space(1))) void*)src,
            (__attribute__((address_space(3))) void*)((uint8_t*)x_lds + (size_t)u * 16),
            16, 0, 0);
    }

    int bidx[K_B];
    #pragma unroll
    for (int k = 0; k < K_B; ++k) bidx[k] = bblk * B_TILE + wave * 8 + k * 4 + bsub;

    // v (v0, or v0+v1 for pass 2), pre-scaled by log2(e) — loop-invariant over p
    float vr[K_B][NC];
    if (PASS >= 1) {
        #pragma unroll
        for (int k = 0; k < K_B; ++k)
            #pragma unroll
            for (int c = 0; c < NC; ++c) {
                float vv = v0[(bidx[k] * NC + c) * ND + d];
                if (PASS == 2) vv += v1[(bidx[k] * NC + c) * ND + d];
                vr[k][c] = vv * LOG2E;
            }
    }

    float sacc[K_B][NC];
    #pragma unroll
    for (int k = 0; k < K_B; ++k)
        #pragma unroll
        for (int c = 0; c < NC; ++c) sacc[k][c] = 0.0f;

    // swizzled read offset for W[ppl,c,d,0:4]: A = d*32 -> A ^ (bit2(d)<<4) ^ (bit3(d)<<5).
    const int lane_rd = (d << 5) ^ ((d & 4) << 2) ^ ((d & 8) << 2);
    const int xswz    = bsub << 4;   // x read swizzle (byte bits 4-5 ^= b&3)

    asm volatile("s_waitcnt vmcnt(0)" ::: "memory");   // W half0 + x staged
    __syncthreads();

    // ================= first half: pp 0..3 (ppl = pp) =================
    #pragma unroll
    for (int pp = 0; pp < 4; ++pp) {
        v2f xv[K_B][4];
        #pragma unroll
        for (int k = 0; k < K_B; ++k) {
            const int xb = ((wave * 8 + k * 4 + bsub) * 256 + pp * 32) ^ xswz;
            const uint8_t* xp = (const uint8_t*)x_lds;
            const float4 a = *(const float4*)(xp + xb);
            const float4 b = *(const float4*)(xp + (xb ^ 16));
            xv[k][0] = v2f{a.x, a.y};
            xv[k][1] = v2f{a.z, a.w};
            xv[k][2] = v2f{b.x, b.y};
            xv[k][3] = v2f{b.z, b.w};
        }
        float uh[K_B][NC];
        #pragma unroll
        for (int c = 0; c < NC; ++c) {
            const uint8_t* pb = (const uint8_t*)w_lds + pp * 5120 + c * 512;
            const float4 wa = *(const float4*)(pb + lane_rd);
            const float4 wb = *(const float4*)(pb + (lane_rd ^ 16));
            const v2f w01{wa.x, wa.y}, w23{wa.z, wa.w};
            const v2f w45{wb.x, wb.y}, w67{wb.z, wb.w};
            #pragma unroll
            for (int k = 0; k < K_B; ++k) {
                v2f acc = w01 * xv[k][0];
                acc = __builtin_elementwise_fma(w23, xv[k][1], acc);
                acc = __builtin_elementwise_fma(w45, xv[k][2], acc);
                acc = __builtin_elementwise_fma(w67, xv[k][3], acc);
                const float u = acc[0] + acc[1];
                if (PASS == 0) sacc[k][c] = fmaf(0.1f, u, sacc[k][c]);
                else           uh[k][c] = u;
            }
        }
        if (PASS >= 1) {
            #pragma unroll
            for (int k = 0; k < K_B; ++k) {
                float lg[NC];
                #pragma unroll
                for (int c = 0; c < NC; ++c)
                    lg[c] = red16_dpp(uh[k][c] * vr[k][c]);
                float ssum = 0.0f;
                float coup[NC];
                #pragma unroll
                for (int c = 0; c < NC; ++c) {
                    coup[c] = __builtin_amdgcn_exp2f(lg[c]);
                    ssum += coup[c];
                }
                const float inv = __builtin_amdgcn_rcpf(ssum);
                #pragma unroll
                for (int c = 0; c < NC; ++c)
                    sacc[k][c] = fmaf(coup[c] * inv, uh[k][c], sacc[k][c]);
            }
        }
    }

    // ================= restage: W half 1 =================
    __syncthreads();                                   // all waves done with half0
    #pragma unroll
    for (int j = 0; j < 5; ++j) {
        const int off = wave * 5120 + j * 1024;
        __builtin_amdgcn_global_load_lds(
            (const __attribute__((address_space(1))) void*)
                (wsrc + W_HALF_BYTES + off + lane_src),
            (__attribute__((address_space(3))) void*)((uint8_t*)w_lds + off),
            16, 0, 0);
    }
    asm volatile("s_waitcnt vmcnt(0)" ::: "memory");   // half1 staged
    __syncthreads();

    // ================= second half: pp 4..7 (ppl = pp-4) =================
    #pragma unroll
    for (int pp = 4; pp < 8; ++pp) {
        v2f xv[K_B][4];
        #pragma unroll
        for (int k = 0; k < K_B; ++k) {
            const int xb = ((wave * 8 + k * 4 + bsub) * 256 + pp * 32) ^ xswz;
            const uint8_t* xp = (const uint8_t*)x_lds;
            const float4 a = *(const float4*)(xp + xb);
            const float4 b = *(const float4*)(xp + (xb ^ 16));
            xv[k][0] = v2f{a.x, a.y};
            xv[k][1] = v2f{a.z, a.w};
            xv[k][2] = v2f{b.x, b.y};
            xv[k][3] = v2f{b.z, b.w};
        }
        float uh[K_B][NC];
        #pragma unroll
        for (int c = 0; c < NC; ++c) {
            const uint8_t* pb = (const uint8_t*)w_lds + (pp - 4) * 5120 + c * 512;
            const float4 wa = *(const float4*)(pb + lane_rd);
            const float4 wb = *(const float4*)(pb + (lane_rd ^ 16));
            const v2f w01{wa.x, wa.y}, w23{wa.z, wa.w};
            const v2f w45{wb.x, wb.y}, w67{wb.z, wb.w};
            #pragma unroll
            for (int k = 0; k < K_B; ++k) {
                v2f acc = w01 * xv[k][0];
                acc = __builtin_elementwise_fma(w23, xv[k][1], acc);
                acc = __builtin_elementwise_fma(w45, xv[k][2], acc);
                acc = __builtin_elementwise_fma(w67, xv[k][3], acc);
                const float u = acc[0] + acc[1];
                if (PASS == 0) sacc[k][c] = fmaf(0.1f, u, sacc[k][c]);
                else           uh[k][c] = u;
            }
        }
        if (PASS >= 1) {
            #pragma unroll
            for (int k = 0; k < K_B; ++k) {
                float lg[NC];
                #pragma unroll
                for (int c = 0; c < NC; ++c)
                    lg[c] = red16_dpp(uh[k][c] * vr[k][c]);
                float ssum = 0.0f;
                float coup[NC];
                #pragma unroll
                for (int c = 0; c < NC; ++c) {
                    coup[c] = __builtin_amdgcn_exp2f(lg[c]);
                    ssum += coup[c];
                }
                const float inv = __builtin_amdgcn_rcpf(ssum);
                #pragma unroll
                for (int c = 0; c < NC; ++c)
                    sacc[k][c] = fmaf(coup[c] * inv, uh[k][c], sacc[k][c]);
            }
        }
    }

    // tail: each thread owns distinct (b,d) -> 10 atomics per k, no redundancy.
    // R9 swizzle keeps all 144 contenders per address on one XCD.
    #pragma unroll
    for (int k = 0; k < K_B; ++k)
        #pragma unroll
        for (int c = 0; c < NC; ++c)
            atomicAdd(&s_out[(bidx[k] * NC + c) * ND + d], sacc[k][c]);
}

// v = (|s|^2/(1+|s|^2)) * s / sqrt(|s|^2+1e-7), norm over d (16-lane rows).
// ZERO_S: re-zero s for the next routing pass (replaces a hipMemsetAsync).
template<bool ZERO_S>
__global__ __launch_bounds__(256)
void caps_squash(float* __restrict__ s, float* __restrict__ v)
{
    const int idx = blockIdx.x * 256 + threadIdx.x;
    const float sv = s[idx];
    if (ZERO_S) s[idx] = 0.0f;
    float sq = red16_dpp(sv * sv);
    const float scale = (sq / (1.0f + sq)) / sqrtf(sq + 1e-7f);
    v[idx] = scale * sv;
}

extern "C" void kernel_launch(void* const* d_in, const int* in_sizes, int n_in,
                              void* d_out, int out_size, void* d_ws, size_t ws_size,
                              hipStream_t stream)
{
    const float* x = (const float*)d_in[0];
    const float* w = (const float*)d_in[1];
    float* out = (float*)d_out;

    float* s  = (float*)d_ws;       // [NB,NC,ND]
    float* v0 = s + SVD;            // [NB,NC,ND]
    float* v1 = out;                // reuse output buffer (overwritten by final squash)

    const dim3 pgrid(NBLK_B * NBLK_P);   // 2304 blocks of 256
    const dim3 pblock(256);
    const dim3 qgrid(SVD / 256);         // 320
    const dim3 qblock(256);

    hipMemsetAsync(s, 0, (size_t)SVD * sizeof(float), stream);
    caps_pass<0><<<pgrid, pblock, 0, stream>>>(x, w, nullptr, nullptr, s);
    caps_squash<true><<<qgrid, qblock, 0, stream>>>(s, v0);
    caps_pass<1><<<pgrid, pblock, 0, stream>>>(x, w, v0, nullptr, s);
    caps_squash<true><<<qgrid, qblock, 0, stream>>>(s, v1);
    caps_pass<2><<<pgrid, pblock, 0, stream>>>(x, w, v0, v1, s);
    caps_squash<false><<<qgrid, qblock, 0, stream>>>(s, out);
}